// Round 8
// baseline (652.373 us; speedup 1.0000x reference)
//
#include <hip/hip_runtime.h>
#include <hip/hip_bf16.h>
#include <cstddef>

// Problem constants
#define S_TOT 3072
#define HID_  1152
#define MLP_  4304
#define MLPP_ 4352   // MLP padded to multiple of 128 (pad is exact zeros)
#define NH_   16
#define HD_   72
#define SEGS_ 6
#define EPS_  1e-5f

typedef __attribute__((ext_vector_type(8))) short short8;
typedef __attribute__((ext_vector_type(4))) float floatx4;
typedef unsigned short ushort;
typedef unsigned int uint;

__device__ __forceinline__ ushort f2bf(float x)
{
    __hip_bfloat16 h = __float2bfloat16(x);
    return *reinterpret_cast<ushort*>(&h);
}
__device__ __forceinline__ float bf2f(ushort u)
{
    __hip_bfloat16 h = *reinterpret_cast<__hip_bfloat16*>(&u);
    return __bfloat162float(h);
}

__device__ __forceinline__ float gelu_tanh(float x)
{
    float x3 = x * x * x;
    return 0.5f * x * (1.0f + tanhf(0.7978845608028654f * (x + 0.044715f * x3)));
}

__device__ __forceinline__ float bperm_f(int srclane, float v)
{
    return __int_as_float(__builtin_amdgcn_ds_bpermute(srclane * 4, __float_as_int(v)));
}

// Direct global->LDS DMA, 16B per lane. LDS dest is wave-uniform base +
// lane*16 (hardware fill order); global source is per-lane.
typedef __attribute__((address_space(3))) void lds_void_t;
typedef __attribute__((address_space(1))) const void gconst_void_t;
__device__ __forceinline__ void gload_lds16(const ushort* g, ushort* l)
{
    __builtin_amdgcn_global_load_lds((gconst_void_t*)g, (lds_void_t*)l, 16, 0, 0);
}

// ---------------------------------------------------------------------------
// LayerNorm -> split bf16 (hi, lo) output. One wave per row.
// ---------------------------------------------------------------------------
__global__ __launch_bounds__(256)
void ln_bf_kernel(const float* __restrict__ x, const float* __restrict__ g,
                  const float* __restrict__ b, ushort* __restrict__ yh,
                  ushort* __restrict__ yl)
{
    int row  = blockIdx.x * 4 + (threadIdx.x >> 6);
    int lane = threadIdx.x & 63;
    const float* xr = x + (size_t)row * HID_;
    float v[18];
    float s = 0.f;
#pragma unroll
    for (int i = 0; i < 18; ++i) { v[i] = xr[lane + i * 64]; s += v[i]; }
#pragma unroll
    for (int o = 32; o; o >>= 1) s += __shfl_xor(s, o);
    float mu = s * (1.0f / (float)HID_);
    float vs = 0.f;
#pragma unroll
    for (int i = 0; i < 18; ++i) { float d = v[i] - mu; vs += d * d; }
#pragma unroll
    for (int o = 32; o; o >>= 1) vs += __shfl_xor(vs, o);
    float rstd = rsqrtf(vs * (1.0f / (float)HID_) + EPS_);
#pragma unroll
    for (int i = 0; i < 18; ++i) {
        int c = lane + i * 64;
        float val = (v[i] - mu) * rstd * g[c] + b[c];
        ushort hi = f2bf(val);
        yh[(size_t)row * HID_ + c] = hi;
        yl[(size_t)row * HID_ + c] = f2bf(val - bf2f(hi));
    }
}

// ---------------------------------------------------------------------------
// Weight convert + transpose: fp32 [Kin][Nin] -> bf16 hi (and optional lo)
// [Nout][Kout] transposed, zero-padded.
// ---------------------------------------------------------------------------
__global__ __launch_bounds__(256)
void convt_kernel(const float* __restrict__ in, ushort* __restrict__ oh,
                  ushort* __restrict__ ol, int Kin, int Nin, int Kout)
{
    __shared__ float t[32][33];
    int n0 = blockIdx.x * 32, k0 = blockIdx.y * 32;
    int tx = threadIdx.x & 31, ty = threadIdx.x >> 5;  // ty 0..7
#pragma unroll
    for (int j = 0; j < 4; ++j) {
        int k = k0 + ty + 8 * j, n = n0 + tx;
        t[ty + 8 * j][tx] = (k < Kin && n < Nin) ? in[(size_t)k * Nin + n] : 0.f;
    }
    __syncthreads();
#pragma unroll
    for (int j = 0; j < 4; ++j) {
        int n = n0 + ty + 8 * j, k = k0 + tx;
        float v = t[tx][ty + 8 * j];
        ushort hi = f2bf(v);
        oh[(size_t)n * Kout + k] = hi;
        if (ol) ol[(size_t)n * Kout + k] = f2bf(v - bf2f(hi));
    }
}

// ---------------------------------------------------------------------------
// 2-term split-bf16 MFMA GEMM: C = act(A @ B^T + bias) (+res)
//   C ~= Ah Bh + Al Bh  (weight-lo dropped: contributes <~1e-3 abs)
// 128x128 tile, BK=32, 4 waves, 4x4 fragments.
// Staging: double-buffered global_load_lds width=16 into LINEAR LDS [128][32]
// (m97 recipe; LDS dest = wave base + lane*16, so wave w stages rows
// [32w,32w+32): lane covers row 32w+lane/4, k-chunk (lane%4)*8).
// One barrier per K-step: prefetch for tile t+1 is issued right AFTER the
// barrier, so its latency hides under tile t's MFMA phase and is drained by
// the NEXT barrier's vmcnt(0).
// ---------------------------------------------------------------------------
template<int ACT, bool HAS_RES, bool OUT_PAIR>
__global__ __launch_bounds__(256)
void gemm_bf16x2_kernel(const ushort* __restrict__ Ah, const ushort* __restrict__ Al,
                        const ushort* __restrict__ Bh,
                        const float* __restrict__ bias, const float* __restrict__ res,
                        float* __restrict__ C, ushort* __restrict__ Chi,
                        ushort* __restrict__ Clo, int M, int N, int K, int Ns)
{
    __shared__ ushort sAh[2][128 * 32];
    __shared__ ushort sAl[2][128 * 32];
    __shared__ ushort sBh[2][128 * 32];

    const int tid = threadIdx.x;
    const int bm = blockIdx.y * 128, bn = blockIdx.x * 128;
    const int lane = tid & 63, wv = tid >> 6;
    const int lm = lane & 15, lg = lane >> 4;
    const int wr = wv >> 1, wc = wv & 1;

    const int l4 = lane >> 2, kb8 = (lane & 3) * 8;
    const size_t ga0 = (size_t)(bm + 32 * wv + l4) * K + kb8;
    const size_t ga1 = ga0 + (size_t)16 * K;
    const size_t gb0 = (size_t)(bn + 32 * wv + l4) * K + kb8;
    const size_t gb1 = gb0 + (size_t)16 * K;
    const int la = wv * 1024;  // wave's chunk base (elements): rows 32w.. of [128][32]

    auto ISSUE = [&](int k0, int b) {
        gload_lds16(Ah + ga0 + k0, &sAh[b][la]);
        gload_lds16(Ah + ga1 + k0, &sAh[b][la + 512]);
        gload_lds16(Al + ga0 + k0, &sAl[b][la]);
        gload_lds16(Al + ga1 + k0, &sAl[b][la + 512]);
        gload_lds16(Bh + gb0 + k0, &sBh[b][la]);
        gload_lds16(Bh + gb1 + k0, &sBh[b][la + 512]);
    };

    floatx4 acc[4][4] = {};
    ISSUE(0, 0);
    const int nt = K / 32;
    for (int t = 0; t < nt; ++t) {
        __syncthreads();   // tile t loads landed (vmcnt(0) at barrier); WAR safe
        if (t + 1 < nt) ISSUE((t + 1) * 32, (t + 1) & 1);
        const int b = t & 1;
        short8 bhf[4];
#pragma unroll
        for (int j = 0; j < 4; ++j)
            bhf[j] = *reinterpret_cast<const short8*>(
                &sBh[b][(wc * 64 + j * 16 + lm) * 32 + 8 * lg]);
#pragma unroll
        for (int i = 0; i < 4; ++i) {
            int ro = (wr * 64 + i * 16 + lm) * 32 + 8 * lg;
            short8 ahf = *reinterpret_cast<const short8*>(&sAh[b][ro]);
            short8 alf = *reinterpret_cast<const short8*>(&sAl[b][ro]);
#pragma unroll
            for (int j = 0; j < 4; ++j) {
                acc[i][j] = __builtin_amdgcn_mfma_f32_16x16x32_bf16(ahf, bhf[j], acc[i][j], 0, 0, 0);
                acc[i][j] = __builtin_amdgcn_mfma_f32_16x16x32_bf16(alf, bhf[j], acc[i][j], 0, 0, 0);
            }
        }
    }

#pragma unroll
    for (int i = 0; i < 4; ++i) {
#pragma unroll
        for (int j = 0; j < 4; ++j) {
#pragma unroll
            for (int r = 0; r < 4; ++r) {
                int m = bm + wr * 64 + i * 16 + lg * 4 + r;
                int n = bn + wc * 64 + j * 16 + lm;
                if (OUT_PAIR) {
                    float v = 0.f;
                    if (n < N) {
                        v = acc[i][j][r] + bias[n];
                        if (ACT == 1) v = gelu_tanh(v);
                    }
                    ushort hi = f2bf(v);
                    Chi[(size_t)m * Ns + n] = hi;
                    Clo[(size_t)m * Ns + n] = f2bf(v - bf2f(hi));
                } else if (n < N) {
                    float v = acc[i][j][r] + bias[n];
                    if (ACT == 1) v = gelu_tanh(v);
                    if (HAS_RES) v += res[(size_t)m * Ns + n];
                    C[(size_t)m * Ns + n] = v;
                }
            }
        }
    }
}

// ---------------------------------------------------------------------------
// QKV post-process: rope Q (pre-scaled by 1/sqrt(HD)), K -> bf16 [NH][S][96]
// (cols 72..95 zero); V -> bf16 transposed [NH][80][S] (rows 72..79 zero).
// ---------------------------------------------------------------------------
__global__ __launch_bounds__(256)
void qkv_post_kernel(const float* __restrict__ qkv, const float* __restrict__ fc,
                     ushort* __restrict__ qh, ushort* __restrict__ kh,
                     ushort* __restrict__ vt)
{
    const int t0 = blockIdx.x * 64, head = blockIdx.y, tid = threadIdx.x;
    const float kscale = 0.11785113019775793f;  // 1/sqrt(72), folded into Q
#pragma unroll
    for (int p = 0; p < 2; ++p) {
        ushort* dst = p ? kh : qh;
        float sc = p ? 1.0f : kscale;
        for (int c = tid; c < 64 * 36; c += 256) {
            int t = c / 36, j = c % 36;
            size_t src = (size_t)(t0 + t) * (3 * HID_) + (size_t)p * HID_ + head * HD_ + 2 * j;
            float a = qkv[src], b = qkv[src + 1];
            float cs = fc[(size_t)(t0 + t) * HD_ + 2 * j];
            float sn = fc[(size_t)(t0 + t) * HD_ + 2 * j + 1];
            float o0 = (a * cs - b * sn) * sc, o1 = (a * sn + b * cs) * sc;
            uint u = (uint)f2bf(o0) | ((uint)f2bf(o1) << 16);
            *reinterpret_cast<uint*>(&dst[((size_t)head * S_TOT + t0 + t) * 96 + 2 * j]) = u;
        }
        for (int c = tid; c < 64 * 12; c += 256) {
            int t = c / 12, q = c % 12;
            *reinterpret_cast<uint*>(&dst[((size_t)head * S_TOT + t0 + t) * 96 + 72 + 2 * q]) = 0u;
        }
    }
    __shared__ ushort vs[72][76];
    for (int c = tid; c < 64 * 72; c += 256) {
        int t = c / 72, d = c % 72;
        vs[d][t] = f2bf(qkv[(size_t)(t0 + t) * (3 * HID_) + 2 * HID_ + head * HD_ + d]);
    }
    __syncthreads();
    for (int c = tid; c < 80 * 16; c += 256) {
        int d = c / 16, ch = c % 16;
        uint lo = 0, hi = 0;
        if (d < HD_) {
            lo = (uint)vs[d][ch * 4]     | ((uint)vs[d][ch * 4 + 1] << 16);
            hi = (uint)vs[d][ch * 4 + 2] | ((uint)vs[d][ch * 4 + 3] << 16);
        }
        uint2 u; u.x = lo; u.y = hi;
        *reinterpret_cast<uint2*>(&vt[((size_t)head * 80 + d) * S_TOT + t0 + ch * 4]) = u;
    }
}

// ---------------------------------------------------------------------------
// Flash attention with SWAPPED QK^T (unchanged from round 7 — known-good).
// ---------------------------------------------------------------------------
#define QBLK 64
#define KVBLK 64
#define KSS 104
#define VTS2 104
#define PLS 72

__global__ __launch_bounds__(256)
void attn_mfma3_kernel(const ushort* __restrict__ qh, const ushort* __restrict__ kh,
                       const ushort* __restrict__ vt, const int* __restrict__ offs,
                       ushort* __restrict__ oh, ushort* __restrict__ ol)
{
    __shared__ alignas(16) ushort Ks[KVBLK * KSS];
    __shared__ alignas(16) ushort Vt[80 * VTS2];
    __shared__ alignas(16) ushort Pl[QBLK * PLS];

    const int qt   = blockIdx.x;
    const int head = blockIdx.y;
    const int tid  = threadIdx.x;
    const int lane = tid & 63;
    const int wv   = tid >> 6;
    const int lm   = lane & 15;
    const int lg   = lane >> 4;
    const int q0   = qt * QBLK;

    int ofv[SEGS_ + 1];
#pragma unroll
    for (int i = 0; i <= SEGS_; ++i) ofv[i] = offs[i];
    auto segof = [&](int t) {
        int s = 0;
#pragma unroll
        for (int i = 1; i <= SEGS_; ++i) s += (t >= ofv[i]);
        return s;
    };

    short8 qf[3];
#pragma unroll
    for (int ks = 0; ks < 3; ++ks)
        qf[ks] = *reinterpret_cast<const short8*>(
            &qh[((size_t)head * S_TOT + q0 + wv * 16 + lm) * 96 + ks * 32 + 8 * lg]);

    const int qseg = segof(q0 + wv * 16 + lm);

    floatx4 of[5] = {};
    float m_run = -1e30f, l_run = 0.f;

    for (int kt = 0; kt < S_TOT / KVBLK; ++kt) {
        const int kv0 = kt * KVBLK;
#pragma unroll
        for (int k = 0; k < 3; ++k) {
            int c = tid + k * 256;
            int r = c / 12, off = (c % 12) * 8;
            *reinterpret_cast<short8*>(&Ks[r * KSS + off]) =
                *reinterpret_cast<const short8*>(&kh[((size_t)head * S_TOT + kv0 + r) * 96 + off]);
        }
#pragma unroll
        for (int k = 0; k < 3; ++k) {
            int c = tid + k * 256;
            if (c < 640) {
                int r = c / 8, off = (c % 8) * 8;
                *reinterpret_cast<short8*>(&Vt[r * VTS2 + off]) =
                    *reinterpret_cast<const short8*>(&vt[((size_t)head * 80 + r) * S_TOT + kv0 + off]);
            }
        }
        __syncthreads();

        floatx4 sf[4];
#pragma unroll
        for (int ct = 0; ct < 4; ++ct) {
            floatx4 acc = {0.f, 0.f, 0.f, 0.f};
#pragma unroll
            for (int ks = 0; ks < 3; ++ks) {
                short8 kb = *reinterpret_cast<const short8*>(
                    &Ks[(ct * 16 + lm) * KSS + ks * 32 + 8 * lg]);
                acc = __builtin_amdgcn_mfma_f32_16x16x32_bf16(kb, qf[ks], acc, 0, 0, 0);
            }
            sf[ct] = acc;
        }

        int ks0 = segof(kv0), ks1 = segof(kv0 + KVBLK - 1);
        float b = 0.f;
        if (ks0 == ks1) {
            b = (qseg == ks0) ? 1.0f : 0.0f;
        } else {
#pragma unroll
            for (int ct = 0; ct < 4; ++ct)
#pragma unroll
                for (int r = 0; r < 4; ++r) {
                    int ksg = segof(kv0 + 16 * ct + 4 * lg + r);
                    sf[ct][r] += (qseg == ksg) ? 1.0f : 0.0f;
                }
        }

        float mx = fmaxf(fmaxf(fmaxf(sf[0][0], sf[0][1]), fmaxf(sf[0][2], sf[0][3])),
                         fmaxf(fmaxf(sf[1][0], sf[1][1]), fmaxf(sf[1][2], sf[1][3])));
        mx = fmaxf(mx, fmaxf(fmaxf(fmaxf(sf[2][0], sf[2][1]), fmaxf(sf[2][2], sf[2][3])),
                             fmaxf(fmaxf(sf[3][0], sf[3][1]), fmaxf(sf[3][2], sf[3][3]))));
        mx = fmaxf(mx, __shfl_xor(mx, 16));
        mx = fmaxf(mx, __shfl_xor(mx, 32));
        float mt = mx + b;

        if (__any((int)(mt > m_run))) {
            float mn = fmaxf(m_run, mt);
            float s = __expf(m_run - mn);
            m_run = mn;
            l_run *= s;
            float s_r[4];
#pragma unroll
            for (int r = 0; r < 4; ++r) s_r[r] = bperm_f(4 * lg + r, s);
#pragma unroll
            for (int ct = 0; ct < 5; ++ct)
#pragma unroll
                for (int r = 0; r < 4; ++r) of[ct][r] *= s_r[r];
        }

        float c = m_run - b;
        float sum = 0.f;
#pragma unroll
        for (int ct = 0; ct < 4; ++ct)
#pragma unroll
            for (int r = 0; r < 4; ++r) {
                float p = __expf(sf[ct][r] - c);
                sf[ct][r] = p;
                sum += p;
            }
        sum += __shfl_xor(sum, 16);
        sum += __shfl_xor(sum, 32);
        l_run += sum;

#pragma unroll
        for (int ct = 0; ct < 4; ++ct) {
            uint w0 = (uint)f2bf(sf[ct][0]) | ((uint)f2bf(sf[ct][1]) << 16);
            uint w1 = (uint)f2bf(sf[ct][2]) | ((uint)f2bf(sf[ct][3]) << 16);
            int e = (wv * 16 + lm) * PLS + 16 * ct + 4 * lg;
            *reinterpret_cast<uint*>(&Pl[e])     = w0;
            *reinterpret_cast<uint*>(&Pl[e + 2]) = w1;
        }

        short8 pa0 = *reinterpret_cast<const short8*>(&Pl[(wv * 16 + lm) * PLS + 8 * lg]);
        short8 pa1 = *reinterpret_cast<const short8*>(&Pl[(wv * 16 + lm) * PLS + 32 + 8 * lg]);

#pragma unroll
        for (int ct = 0; ct < 5; ++ct) {
            short8 v0 = *reinterpret_cast<const short8*>(&Vt[(ct * 16 + lm) * VTS2 + 8 * lg]);
            short8 v1 = *reinterpret_cast<const short8*>(&Vt[(ct * 16 + lm) * VTS2 + 32 + 8 * lg]);
            of[ct] = __builtin_amdgcn_mfma_f32_16x16x32_bf16(pa0, v0, of[ct], 0, 0, 0);
            of[ct] = __builtin_amdgcn_mfma_f32_16x16x32_bf16(pa1, v1, of[ct], 0, 0, 0);
        }
        __syncthreads();
    }

    float invl = 1.0f / l_run;
    float inv_r[4];
#pragma unroll
    for (int r = 0; r < 4; ++r) inv_r[r] = bperm_f(4 * lg + r, invl);
#pragma unroll
    for (int ct = 0; ct < 5; ++ct) {
        int d = ct * 16 + lm;
        if (d < HD_) {
#pragma unroll
            for (int r = 0; r < 4; ++r) {
                int row = q0 + wv * 16 + lg * 4 + r;
                float v = of[ct][r] * inv_r[r];
                ushort hi = f2bf(v);
                oh[(size_t)row * HID_ + head * HD_ + d] = hi;
                ol[(size_t)row * HID_ + head * HD_ + d] = f2bf(v - bf2f(hi));
            }
        }
    }
}

// ---------------------------------------------------------------------------
// Launch. Workspace layout identical to rounds 5-7 (peak 101.8 MB, proven OK).
// ---------------------------------------------------------------------------
extern "C" void kernel_launch(void* const* d_in, const int* in_sizes, int n_in,
                              void* d_out, int out_size, void* d_ws, size_t ws_size,
                              hipStream_t stream)
{
    const float* x      = (const float*)d_in[0];
    const int*   offs   = (const int*)  d_in[1];
    const float* fc     = (const float*)d_in[2];
    const float* ln0_g  = (const float*)d_in[3];
    const float* ln0_b  = (const float*)d_in[4];
    const float* wqkv_w = (const float*)d_in[5];
    const float* wqkv_b = (const float*)d_in[6];
    const float* wo_w   = (const float*)d_in[7];
    const float* wo_b   = (const float*)d_in[8];
    const float* ln1_g  = (const float*)d_in[9];
    const float* ln1_b  = (const float*)d_in[10];
    const float* w1     = (const float*)d_in[11];
    const float* b1     = (const float*)d_in[12];
    const float* w2     = (const float*)d_in[13];
    const float* b2     = (const float*)d_in[14];
    float* outp = (float*)d_out;

    char* base = (char*)d_ws;
    const size_t SZ_X2    = (size_t)S_TOT * HID_ * 4;
    const size_t SZ_HPAIR = (size_t)S_TOT * HID_ * 2;
    const size_t SZ_W1E   = (size_t)MLPP_ * HID_ * 2;
    const size_t SZ_QKV   = (size_t)S_TOT * 3 * HID_ * 4;

    float*  x2      = (float*)(base + 0);
    float*  qkv     = (float*)(base + 0);
    ushort* h2_h    = (ushort*)(base + SZ_X2);
    ushort* h2_l    = h2_h + (size_t)S_TOT * HID_;
    ushort* woT_h   = (ushort*)(base + SZ_X2);
    ushort* w2T_h   = (ushort*)(base + SZ_X2);
    ushort* w1T_h   = (ushort*)(base + SZ_X2 + 2 * SZ_HPAIR);
    ushort* mid_h   = (ushort*)(base + SZ_X2 + 2 * SZ_HPAIR + 2 * SZ_W1E);
    ushort* mid_l   = mid_h + (size_t)S_TOT * MLPP_;
    ushort* h_h     = (ushort*)(base + SZ_QKV);
    ushort* h_l     = h_h + (size_t)S_TOT * HID_;
    ushort* aout_h  = h_h;
    ushort* aout_l  = h_l;
    ushort* wqkvT_h = (ushort*)(base + SZ_QKV + 2 * SZ_HPAIR);
    ushort* qh      = (ushort*)(base + SZ_QKV + 2 * SZ_HPAIR);
    ushort* kh      = qh + (size_t)NH_ * S_TOT * 96;
    ushort* vt      = kh + (size_t)NH_ * S_TOT * 96;
    // qh aliases wqkvT_h — wqkvT live L1-L3, qh live L4-L5: disjoint. OK.

    // L1: wqkv convert+transpose (hi only)
    convt_kernel<<<dim3(3456 / 32, 1152 / 32), 256, 0, stream>>>(
        wqkv_w, wqkvT_h, nullptr, 1152, 3456, 1152);
    // L2: h = LN0(x)
    ln_bf_kernel<<<S_TOT / 4, 256, 0, stream>>>(x, ln0_g, ln0_b, h_h, h_l);
    // L3: qkv = h @ wqkv + b (fp32)
    gemm_bf16x2_kernel<0, false, false><<<dim3(3456 / 128, S_TOT / 128), 256, 0, stream>>>(
        h_h, h_l, wqkvT_h, wqkv_b, nullptr, qkv, nullptr, nullptr,
        S_TOT, 3456, 1152, 3456);
    // L4: rope + bf16 pack (+1/sqrt(HD) folded into Q) + V transpose
    qkv_post_kernel<<<dim3(S_TOT / 64, NH_), 256, 0, stream>>>(qkv, fc, qh, kh, vt);
    // L5: attention -> aout pair
    attn_mfma3_kernel<<<dim3(S_TOT / QBLK, NH_), 256, 0, stream>>>(
        qh, kh, vt, offs, aout_h, aout_l);
    // L6: wo convert+transpose
    convt_kernel<<<dim3(1152 / 32, 1152 / 32), 256, 0, stream>>>(
        wo_w, woT_h, nullptr, 1152, 1152, 1152);
    // L7: x2 = x + aout @ wo + b
    gemm_bf16x2_kernel<0, true, false><<<dim3(HID_ / 128, S_TOT / 128), 256, 0, stream>>>(
        aout_h, aout_l, woT_h, wo_b, x, x2, nullptr, nullptr,
        S_TOT, HID_, 1152, HID_);
    // L8: h2 = LN1(x2)
    ln_bf_kernel<<<S_TOT / 4, 256, 0, stream>>>(x2, ln1_g, ln1_b, h2_h, h2_l);
    // L9: w1 convert+transpose
    convt_kernel<<<dim3(MLPP_ / 32, 1152 / 32), 256, 0, stream>>>(
        w1, w1T_h, nullptr, 1152, MLP_, 1152);
    // L10: mid = gelu(h2 @ w1 + b1)
    gemm_bf16x2_kernel<1, false, true><<<dim3(MLPP_ / 128, S_TOT / 128), 256, 0, stream>>>(
        h2_h, h2_l, w1T_h, b1, nullptr, nullptr, mid_h, mid_l,
        S_TOT, MLP_, 1152, MLPP_);
    // L11: w2 convert+transpose
    convt_kernel<<<dim3(1152 / 32, MLPP_ / 32), 256, 0, stream>>>(
        w2, w2T_h, nullptr, MLP_, 1152, MLPP_);
    // L12: out = x2 + mid @ w2 + b2
    gemm_bf16x2_kernel<0, true, false><<<dim3(HID_ / 128, S_TOT / 128), 256, 0, stream>>>(
        mid_h, mid_l, w2T_h, b2, x2, outp, nullptr, nullptr,
        S_TOT, HID_, MLPP_, HID_);
}